// Round 1
// baseline (1169.049 us; speedup 1.0000x reference)
//
#include <hip/hip_runtime.h>
#include <hip/hip_bf16.h>

#define HW 4096          // 64*64 spatial
#define IMW 64
#define BATCH 64
#define NPIX (BATCH * HW)   // 262144

// ---------------------------------------------------------------------------
// Direct 3x3 conv, pad=1. One thread = one pixel, computes COUT channels.
// Weights staged in LDS as [ci*9+k][co] -> wave-uniform broadcast reads.
// ---------------------------------------------------------------------------
template <int CIN, int COUT, bool RELU, bool BIAS>
__global__ void conv3x3_kernel(const float* __restrict__ in,
                               const float* __restrict__ w,
                               const float* __restrict__ bias,
                               float* __restrict__ out) {
    __shared__ float lw[CIN * 9 * COUT];
    for (int idx = threadIdx.x; idx < CIN * 9 * COUT; idx += blockDim.x) {
        int co = idx % COUT;
        int rest = idx / COUT;              // ci*9 + k
        lw[idx] = w[(size_t)co * CIN * 9 + rest];
    }
    __syncthreads();

    int p = blockIdx.x * blockDim.x + threadIdx.x;
    if (p >= NPIX) return;
    int b = p >> 12;
    int pos = p & 4095;
    int y = pos >> 6;
    int x = pos & 63;

    float acc[COUT];
#pragma unroll
    for (int co = 0; co < COUT; ++co) {
        float bv = 0.f;
        if constexpr (BIAS) bv = bias[co];
        acc[co] = bv;
    }

#pragma unroll 1
    for (int ci = 0; ci < CIN; ++ci) {
        const float* ip = in + ((size_t)(b * CIN + ci) << 12);
        float v[9];
#pragma unroll
        for (int dy = 0; dy < 3; ++dy) {
#pragma unroll
            for (int dx = 0; dx < 3; ++dx) {
                int yy = y + dy - 1, xx = x + dx - 1;
                bool ok = (yy >= 0) & (yy < IMW) & (xx >= 0) & (xx < IMW);
                v[dy * 3 + dx] = ok ? ip[yy * IMW + xx] : 0.f;
            }
        }
#pragma unroll
        for (int k = 0; k < 9; ++k) {
            float vv = v[k];
            const float* wrow = &lw[(ci * 9 + k) * COUT];
#pragma unroll
            for (int co = 0; co < COUT; ++co)
                acc[co] = fmaf(wrow[co], vv, acc[co]);
        }
    }

#pragma unroll
    for (int co = 0; co < COUT; ++co) {
        float o = acc[co];
        if (RELU) o = fmaxf(o, 0.f);
        out[((size_t)(b * COUT + co) << 12) + pos] = o;
    }
}

// ---------------------------------------------------------------------------
// Deformable conv 3x3 (pad=1), per reference semantics.
// offset layout: channel 2k = dy, 2k+1 = dx, k = ky*3+kx.
// One thread = one pixel, computes COUT_BLK channels (blockIdx.y selects blk).
// ---------------------------------------------------------------------------
template <int CIN, int COUT_TOT, int COUT_BLK, bool RELU>
__global__ void deform_conv_kernel(const float* __restrict__ in,
                                   const float* __restrict__ off,
                                   const float* __restrict__ w,
                                   float* __restrict__ out) {
    __shared__ float lw[CIN * 9 * COUT_BLK];
    int co_base = blockIdx.y * COUT_BLK;
    for (int idx = threadIdx.x; idx < CIN * 9 * COUT_BLK; idx += blockDim.x) {
        int co = idx % COUT_BLK;
        int rest = idx / COUT_BLK;          // ci*9 + k
        lw[idx] = w[(size_t)(co_base + co) * CIN * 9 + rest];
    }
    __syncthreads();

    int p = blockIdx.x * blockDim.x + threadIdx.x;
    if (p >= NPIX) return;
    int b = p >> 12;
    int pos = p & 4095;
    int y = pos >> 6;
    int x = pos & 63;

    float acc[COUT_BLK];
#pragma unroll
    for (int co = 0; co < COUT_BLK; ++co) acc[co] = 0.f;

    const float* ib = in + ((size_t)b * CIN << 12);
    const float* ob = off + ((size_t)b * 18 << 12);

#pragma unroll 1
    for (int k = 0; k < 9; ++k) {
        int ky = k / 3, kx = k % 3;
        float py = (float)(y + ky - 1) + ob[(size_t)(2 * k) * HW + pos];
        float px = (float)(x + kx - 1) + ob[(size_t)(2 * k + 1) * HW + pos];
        float fy = floorf(py), fx = floorf(px);
        float wy = py - fy, wx = px - fx;
        int y0 = (int)fy, x0 = (int)fx;
        int y1 = y0 + 1, x1 = x0 + 1;
        bool vy0 = (y0 >= 0) & (y0 < IMW);
        bool vy1 = (y1 >= 0) & (y1 < IMW);
        bool vx0 = (x0 >= 0) & (x0 < IMW);
        bool vx1 = (x1 >= 0) & (x1 < IMW);
        int cy0 = min(max(y0, 0), IMW - 1), cy1 = min(max(y1, 0), IMW - 1);
        int cx0 = min(max(x0, 0), IMW - 1), cx1 = min(max(x1, 0), IMW - 1);
        int i00 = cy0 * IMW + cx0, i01 = cy0 * IMW + cx1;
        int i10 = cy1 * IMW + cx0, i11 = cy1 * IMW + cx1;
        float w00 = (1.f - wy) * (1.f - wx) * ((vy0 & vx0) ? 1.f : 0.f);
        float w01 = (1.f - wy) * wx * ((vy0 & vx1) ? 1.f : 0.f);
        float w10 = wy * (1.f - wx) * ((vy1 & vx0) ? 1.f : 0.f);
        float w11 = wy * wx * ((vy1 & vx1) ? 1.f : 0.f);

#pragma unroll 1
        for (int ci = 0; ci < CIN; ++ci) {
            const float* ip = ib + ((size_t)ci << 12);
            float s = w00 * ip[i00] + w01 * ip[i01] + w10 * ip[i10] + w11 * ip[i11];
            const float* wrow = &lw[(ci * 9 + k) * COUT_BLK];
#pragma unroll
            for (int co = 0; co < COUT_BLK; ++co)
                acc[co] = fmaf(wrow[co], s, acc[co]);
        }
    }

#pragma unroll
    for (int co = 0; co < COUT_BLK; ++co) {
        float o = acc[co];
        if (RELU) o = fmaxf(o, 0.f);
        out[((size_t)(b * COUT_TOT + co_base + co) << 12) + pos] = o;
    }
}

// ---------------------------------------------------------------------------
// BatchNorm stats: partial sums (per-channel, split into `parts` blocks),
// then finalize into scale/shift.
// ---------------------------------------------------------------------------
__global__ void bn_partial_kernel(const float* __restrict__ src, int C, int parts,
                                  float* __restrict__ sums /* [2*C] */) {
    int c = blockIdx.x / parts;
    int part = blockIdx.x % parts;
    const int N = NPIX;               // elements per channel
    int chunk = N / parts;
    int start = part * chunk;
    float s = 0.f, q = 0.f;
    for (int i = start + threadIdx.x; i < start + chunk; i += blockDim.x) {
        int bb = i >> 12, pos = i & 4095;
        float v = src[((size_t)(bb * C + c) << 12) + pos];
        s += v;
        q += v * v;
    }
    __shared__ float ls[256], lq[256];
    ls[threadIdx.x] = s;
    lq[threadIdx.x] = q;
    __syncthreads();
    for (int st = 128; st > 0; st >>= 1) {
        if (threadIdx.x < st) {
            ls[threadIdx.x] += ls[threadIdx.x + st];
            lq[threadIdx.x] += lq[threadIdx.x + st];
        }
        __syncthreads();
    }
    if (threadIdx.x == 0) {
        atomicAdd(&sums[c], ls[0]);
        atomicAdd(&sums[C + c], lq[0]);
    }
}

__global__ void bn_finalize_kernel(const float* __restrict__ sums, int C,
                                   const float* __restrict__ g,
                                   const float* __restrict__ b,
                                   float* __restrict__ scale,
                                   float* __restrict__ shift) {
    int c = threadIdx.x;
    if (c >= C) return;
    const float invN = 1.f / (float)NPIX;
    float mean = sums[c] * invN;
    float var = sums[C + c] * invN - mean * mean;
    float sc = g[c] * rsqrtf(var + 1e-5f);
    scale[c] = sc;
    shift[c] = b[c] - mean * sc;
}

__global__ void bn_apply_kernel(float* __restrict__ data, int C,
                                const float* __restrict__ scale,
                                const float* __restrict__ shift) {
    size_t idx = (size_t)blockIdx.x * blockDim.x + threadIdx.x;
    size_t total = (size_t)BATCH * C * HW;
    if (idx >= total) return;
    int c = (int)((idx >> 12) % (size_t)C);
    data[idx] = data[idx] * scale[c] + shift[c];
}

// ---------------------------------------------------------------------------
// Quadrant pool: one block per (b,c) plane -> 4 quadrant means.
// ---------------------------------------------------------------------------
__global__ void pool_kernel(const float* __restrict__ em, float* __restrict__ pw) {
    int bc = blockIdx.x;               // b*64 + c
    int t = threadIdx.x;               // 256 threads, 16 elems each
    const float* base = em + ((size_t)bc << 12);
    int pos = t * 16;
    int y = pos >> 6;
    int xq = (pos & 63) >> 5;
    int quad = ((y >= 32) ? 2 : 0) + xq;
    float s = 0.f;
#pragma unroll
    for (int k = 0; k < 16; ++k) s += base[pos + k];
    __shared__ float qs[4];
    if (t < 4) qs[t] = 0.f;
    __syncthreads();
    atomicAdd(&qs[quad], s);
    __syncthreads();
    if (t < 4) pw[bc * 4 + t] = qs[t] * (1.f / 1024.f);
}

// ---------------------------------------------------------------------------
// FC (256 -> 10) + softmax per image.
// ---------------------------------------------------------------------------
__global__ void fc_softmax_kernel(const float* __restrict__ pw,
                                  const float* __restrict__ fw,
                                  const float* __restrict__ fb,
                                  float* __restrict__ out) {
    int b = blockIdx.x;
    int t = threadIdx.x;               // 64 threads
    __shared__ float logits[10];
    if (t < 10) {
        float acc = fb[t];
        const float* p = pw + b * 256;
        for (int q = 0; q < 256; ++q) acc = fmaf(p[q], fw[t * 256 + q], acc);
        logits[t] = acc;
    }
    __syncthreads();
    if (t == 0) {
        float m = -1e30f;
        for (int q = 0; q < 10; ++q) m = fmaxf(m, logits[q]);
        float e[10], sum = 0.f;
        for (int q = 0; q < 10; ++q) { e[q] = expf(logits[q] - m); sum += e[q]; }
        float inv = 1.f / sum;
        for (int q = 0; q < 10; ++q) out[b * 10 + q] = e[q] * inv;
    }
}

// ---------------------------------------------------------------------------
extern "C" void kernel_launch(void* const* d_in, const int* in_sizes, int n_in,
                              void* d_out, int out_size, void* d_ws, size_t ws_size,
                              hipStream_t stream) {
    (void)in_sizes; (void)n_in; (void)out_size; (void)ws_size;

    const float* x   = (const float*)d_in[0];
    const float* w1  = (const float*)d_in[1];
    const float* g1  = (const float*)d_in[2];
    const float* b1  = (const float*)d_in[3];
    const float* w2  = (const float*)d_in[4];
    const float* bc2 = (const float*)d_in[5];
    const float* g2  = (const float*)d_in[6];
    const float* b2  = (const float*)d_in[7];
    const float* w3  = (const float*)d_in[8];
    const float* wd1 = (const float*)d_in[9];
    const float* g3  = (const float*)d_in[10];
    const float* b3  = (const float*)d_in[11];
    const float* w4  = (const float*)d_in[12];
    const float* bc4 = (const float*)d_in[13];
    const float* wd2 = (const float*)d_in[14];
    const float* g4  = (const float*)d_in[15];
    const float* b4  = (const float*)d_in[16];
    const float* fw  = (const float*)d_in[17];
    const float* fb  = (const float*)d_in[18];

    float* out = (float*)d_out;
    float* softout = out;                       // 64*10
    float* em = out + 640;                      // 64*64*4096

    float* ws = (float*)d_ws;
    float* h1   = ws;                           // 64* 8*4096 = 2,097,152
    float* h2   = h1 + (size_t)2097152;         // 64*20*4096 = 5,242,880
    float* h3   = h2 + (size_t)5242880;         // 64*40*4096 = 10,485,760
    float* offb = h3 + (size_t)10485760;        // 64*18*4096 = 4,718,592
    float* sums = offb + (size_t)4718592;       // 128
    float* scale = sums + 128;                  // 64
    float* shift = scale + 64;                  // 64
    float* pw    = shift + 64;                  // 64*256

    const int PARTS = 32;
    dim3 blk(256);
    dim3 gpix((NPIX + 255) / 256);

    // stage 1: conv1 + relu -> bn
    conv3x3_kernel<3, 8, true, false><<<gpix, blk, 0, stream>>>(x, w1, nullptr, h1);
    hipMemsetAsync(sums, 0, 128 * sizeof(float), stream);
    bn_partial_kernel<<<8 * PARTS, 256, 0, stream>>>(h1, 8, PARTS, sums);
    bn_finalize_kernel<<<1, 64, 0, stream>>>(sums, 8, g1, b1, scale, shift);
    bn_apply_kernel<<<(64 * 8 * 4096 + 255) / 256, 256, 0, stream>>>(h1, 8, scale, shift);

    // stage 2: conv2 (+bias) + relu -> bn
    conv3x3_kernel<8, 20, true, true><<<gpix, blk, 0, stream>>>(h1, w2, bc2, h2);
    hipMemsetAsync(sums, 0, 128 * sizeof(float), stream);
    bn_partial_kernel<<<20 * PARTS, 256, 0, stream>>>(h2, 20, PARTS, sums);
    bn_finalize_kernel<<<1, 64, 0, stream>>>(sums, 20, g2, b2, scale, shift);
    bn_apply_kernel<<<(64 * 20 * 4096 + 255) / 256, 256, 0, stream>>>(h2, 20, scale, shift);

    // stage 3: offset conv (no bias, no relu), deform conv 1 + relu -> bn
    conv3x3_kernel<20, 18, false, false><<<gpix, blk, 0, stream>>>(h2, w3, nullptr, offb);
    deform_conv_kernel<20, 40, 40, true><<<gpix, blk, 0, stream>>>(h2, offb, wd1, h3);
    hipMemsetAsync(sums, 0, 128 * sizeof(float), stream);
    bn_partial_kernel<<<40 * PARTS, 256, 0, stream>>>(h3, 40, PARTS, sums);
    bn_finalize_kernel<<<1, 64, 0, stream>>>(sums, 40, g3, b3, scale, shift);
    bn_apply_kernel<<<(64 * 40 * 4096 + 255) / 256, 256, 0, stream>>>(h3, 40, scale, shift);

    // stage 4: offset conv 2 (+bias), deform conv 2 + relu -> bn (into em)
    conv3x3_kernel<40, 18, false, true><<<gpix, blk, 0, stream>>>(h3, w4, bc4, offb);
    {
        dim3 g2d(gpix.x, 2);
        deform_conv_kernel<40, 64, 32, true><<<g2d, blk, 0, stream>>>(h3, offb, wd2, em);
    }
    hipMemsetAsync(sums, 0, 128 * sizeof(float), stream);
    bn_partial_kernel<<<64 * PARTS, 256, 0, stream>>>(em, 64, PARTS, sums);
    bn_finalize_kernel<<<1, 64, 0, stream>>>(sums, 64, g4, b4, scale, shift);
    bn_apply_kernel<<<(64 * 64 * 4096 + 255) / 256, 256, 0, stream>>>(em, 64, scale, shift);

    // head: quadrant pool -> FC -> softmax
    pool_kernel<<<64 * 64, 256, 0, stream>>>(em, pw);
    fc_softmax_kernel<<<64, 64, 0, stream>>>(pw, fw, fb, softout);
}